// Round 1
// baseline (1191.670 us; speedup 1.0000x reference)
//
#include <hip/hip_runtime.h>
#include <math.h>

#define NTOK   256000
#define TOKB   16000
#define EPS    1e-5f

__device__ __forceinline__ float gelu_f(float x){
  return 0.5f*x*(1.0f+erff(x*0.70710678118654752440f));
}
__device__ __forceinline__ float elu1_f(float x){
  return x>0.0f ? x+1.0f : expf(x);   // elu(x)+1
}

// ---------------------------------------------------------------------------
// Tokenizer: band conv(51) -> 1x1 conv(4->32) -> BN -> GELU -> avgpool(4)
// one block per (b,e) row; thread tp handles one pooled output position
// ---------------------------------------------------------------------------
__global__ __launch_bounds__(256) void k_tokenize(
    const float* __restrict__ x, const float* __restrict__ band_w,
    const float* __restrict__ pw_w, const float* __restrict__ bn_g,
    const float* __restrict__ bn_b, const float* __restrict__ bn_m,
    const float* __restrict__ bn_v, float* __restrict__ hout)
{
  __shared__ float sx[1050];
  __shared__ float sbw[4][51];
  __shared__ float spw[32][4];
  __shared__ float sscale[32], sshift[32];
  const int tid = threadIdx.x;
  const int b = blockIdx.x >> 6, e = blockIdx.x & 63;
  const float* xr = x + (size_t)(b*64 + e)*1000;
  for (int i=tid;i<1050;i+=256){ int t=i-25; sx[i]=(t>=0&&t<1000)?xr[t]:0.0f; }
  for (int i=tid;i<204;i+=256){ sbw[i/51][i%51] = band_w[i]; }
  for (int i=tid;i<128;i+=256){ spw[i>>2][i&3] = pw_w[i]; }
  if (tid<32){ float sc = bn_g[tid]*rsqrtf(bn_v[tid]+EPS);
               sscale[tid]=sc; sshift[tid]=bn_b[tid]-bn_m[tid]*sc; }
  __syncthreads();
  const int tp = tid;
  if (tp < 250) {
    float acc[32];
    #pragma unroll
    for (int o=0;o<32;o++) acc[o]=0.0f;
    for (int j=0;j<4;j++){
      const int t = 4*tp+j;
      float c0=0,c1=0,c2=0,c3=0;
      for (int k=0;k<51;k++){
        float xv = sx[t+k];
        c0 += xv*sbw[0][k]; c1 += xv*sbw[1][k];
        c2 += xv*sbw[2][k]; c3 += xv*sbw[3][k];
      }
      #pragma unroll
      for (int o=0;o<32;o++){
        float hv = spw[o][0]*c0 + spw[o][1]*c1 + spw[o][2]*c2 + spw[o][3]*c3;
        hv = hv*sscale[o] + sshift[o];
        acc[o] += gelu_f(hv);
      }
    }
    const int tok = b*TOKB + e*250 + tp;
    float4* dst = (float4*)(hout + (size_t)tok*32);
    #pragma unroll
    for (int o8=0;o8<8;o8++)
      dst[o8] = make_float4(acc[o8*4]*0.25f, acc[o8*4+1]*0.25f,
                            acc[o8*4+2]*0.25f, acc[o8*4+3]*0.25f);
  }
}

// ---------------------------------------------------------------------------
// Pass A: per 128-token tile: ln1 -> k,v -> K-features -> partial KV[h,f,d]
// phase1: 2 threads per token compute k,v into LDS; phase2: thread=(h,f)
// ---------------------------------------------------------------------------
__global__ __launch_bounds__(256) void k_kv_partial(
    const float* __restrict__ hbuf, const float* __restrict__ ln1_g,
    const float* __restrict__ ln1_b, const float* __restrict__ wqkv,
    const float* __restrict__ proj_mat, float* __restrict__ kvpart, int l)
{
  __shared__ float sk[128][33];
  __shared__ float sv[128][33];
  __shared__ float swk[32][64];   // wqkv cols 32..95 (k then v)
  __shared__ float sg[32], sb[32];
  const int tid = threadIdx.x;
  const float* W = wqkv + l*32*96;
  for (int i=tid;i<2048;i+=256){ swk[i>>6][i&63] = W[(i>>6)*96 + 32 + (i&63)]; }
  if (tid<32){ sg[tid]=ln1_g[l*32+tid]; sb[tid]=ln1_b[l*32+tid]; }
  __syncthreads();
  {
    const int tloc = tid>>1, half = tid&1;
    const int tok = blockIdx.x*128 + tloc;
    float hx[32];
    const float4* src = (const float4*)(hbuf + (size_t)tok*32);
    #pragma unroll
    for (int i=0;i<8;i++){ float4 v4=src[i]; hx[4*i]=v4.x; hx[4*i+1]=v4.y; hx[4*i+2]=v4.z; hx[4*i+3]=v4.w; }
    float mu=0;
    #pragma unroll
    for (int i=0;i<32;i++) mu += hx[i];
    mu *= (1.0f/32.0f);
    float vs=0;
    #pragma unroll
    for (int i=0;i<32;i++){ float d=hx[i]-mu; vs += d*d; }
    const float inv = rsqrtf(vs*(1.0f/32.0f)+EPS);
    float xn[32];
    #pragma unroll
    for (int i=0;i<32;i++) xn[i] = (hx[i]-mu)*inv*sg[i]+sb[i];
    const int j0 = half*16;
    for (int jj=0;jj<16;jj++){
      const int j = j0+jj;
      float ka=0, va=0;
      #pragma unroll
      for (int i=0;i<32;i++){ ka += xn[i]*swk[i][j]; va += xn[i]*swk[i][32+j]; }
      sk[tloc][j]=ka; sv[tloc][j]=va;
    }
  }
  __syncthreads();
  const int hh = tid>>6, f = tid&63;
  float pmv[8];
  #pragma unroll
  for (int d=0;d<8;d++) pmv[d] = proj_mat[((size_t)(l*4+hh)*8+d)*64 + f];
  float acc[8];
  #pragma unroll
  for (int d=0;d<8;d++) acc[d]=0.0f;
  #pragma unroll 4
  for (int t=0;t<128;t++){
    float kd=0;
    #pragma unroll
    for (int d=0;d<8;d++) kd += sk[t][hh*8+d]*pmv[d];
    const float Kf = elu1_f(kd);
    #pragma unroll
    for (int d=0;d<8;d++) acc[d] += Kf*sv[t][hh*8+d];
  }
  float* dst = kvpart + (size_t)blockIdx.x*2048 + tid*8;
  #pragma unroll
  for (int d=0;d<8;d++) dst[d]=acc[d];
}

// fixed-order hierarchical KV reduction: 2000 partials -> 10 chunks -> final
__global__ __launch_bounds__(256) void k_kv_reduce1(
    const float* __restrict__ kvpart, float* __restrict__ p2)
{
  const int chunk = blockIdx.x >> 3;                 // 0..9
  const int e = (blockIdx.x&7)*256 + threadIdx.x;    // 0..2047
  float acc=0.0f;
  const int base = chunk*200;
  for (int ab=0; ab<200; ab++) acc += kvpart[(size_t)(base+ab)*2048 + e];
  p2[chunk*2048 + e] = acc;
}

__global__ __launch_bounds__(256) void k_kv_reduce2(
    const float* __restrict__ p2, float* __restrict__ KV, float* __restrict__ KVs)
{
  const int hf = threadIdx.x;
  float acc[8];
  #pragma unroll
  for (int d=0;d<8;d++) acc[d]=0.0f;
  for (int c=0;c<10;c++){
    #pragma unroll
    for (int d=0;d<8;d++) acc[d] += p2[c*2048 + hf*8 + d];
  }
  float s=0.0f;
  #pragma unroll
  for (int d=0;d<8;d++){ KV[hf*8+d]=acc[d]; s+=acc[d]; }
  KVs[hf]=s;
}

// ---------------------------------------------------------------------------
// Pass C: per token: ln1 -> q -> Qfeat(streamed) -> attn out -> proj + res
//                    -> ln2 -> FFN(gelu) + res.  All weights in LDS.
// ---------------------------------------------------------------------------
__global__ __launch_bounds__(256) void k_attn_ffn(
    float* __restrict__ hbuf,
    const float* __restrict__ ln1_g, const float* __restrict__ ln1_b,
    const float* __restrict__ wqkv, const float* __restrict__ proj_mat,
    const float* __restrict__ wproj, const float* __restrict__ bproj,
    const float* __restrict__ ln2_g, const float* __restrict__ ln2_b,
    const float* __restrict__ w1, const float* __restrict__ b1,
    const float* __restrict__ w2, const float* __restrict__ b2,
    const float* __restrict__ KV, const float* __restrict__ KVs, int l)
{
  __shared__ float swq[32][32];
  __shared__ float spm[4][8][64];
  __shared__ float sKV[4][64][8];
  __shared__ float sKVs[4][64];
  __shared__ float swp[32][32];
  __shared__ float sw1[32][64];
  __shared__ float sw2[64][32];
  __shared__ float s1g[32],s1b[32],s2g[32],s2b[32],sbp[32],sb1[64],sb2[32];
  const int tid = threadIdx.x;
  for (int i=tid;i<1024;i+=256) swq[i>>5][i&31] = wqkv[l*3072 + (i>>5)*96 + (i&31)];
  for (int i=tid;i<2048;i+=256) (&spm[0][0][0])[i] = proj_mat[l*2048+i];
  for (int i=tid;i<2048;i+=256) (&sKV[0][0][0])[i] = KV[i];
  if (tid<256) (&sKVs[0][0])[tid] = KVs[tid];
  for (int i=tid;i<1024;i+=256) (&swp[0][0])[i] = wproj[l*1024+i];
  for (int i=tid;i<2048;i+=256) (&sw1[0][0])[i] = w1[l*2048+i];
  for (int i=tid;i<2048;i+=256) (&sw2[0][0])[i] = w2[l*2048+i];
  if (tid<32){ s1g[tid]=ln1_g[l*32+tid]; s1b[tid]=ln1_b[l*32+tid];
               s2g[tid]=ln2_g[l*32+tid]; s2b[tid]=ln2_b[l*32+tid];
               sbp[tid]=bproj[l*32+tid]; sb2[tid]=b2[l*32+tid]; }
  if (tid<64) sb1[tid]=b1[l*64+tid];
  __syncthreads();

  const int tok = blockIdx.x*256 + tid;
  float hx[32];
  float4* hp = (float4*)(hbuf + (size_t)tok*32);
  #pragma unroll
  for (int i=0;i<8;i++){ float4 v4=hp[i]; hx[4*i]=v4.x; hx[4*i+1]=v4.y; hx[4*i+2]=v4.z; hx[4*i+3]=v4.w; }
  // ln1
  float mu=0;
  #pragma unroll
  for (int i=0;i<32;i++) mu += hx[i];
  mu *= (1.0f/32.0f);
  float vs=0;
  #pragma unroll
  for (int i=0;i<32;i++){ float d=hx[i]-mu; vs += d*d; }
  float inv = rsqrtf(vs*(1.0f/32.0f)+EPS);
  float q[32];
  {
    float xn[32];
    #pragma unroll
    for (int i=0;i<32;i++) xn[i] = (hx[i]-mu)*inv*s1g[i]+s1b[i];
    for (int j=0;j<32;j++){
      float a=0;
      #pragma unroll
      for (int i=0;i<32;i++) a += xn[i]*swq[i][j];
      q[j]=a;
    }
  }
  // attention via global KV
  float att[32];
  for (int hh=0;hh<4;hh++){
    float den=0;
    float ao[8];
    #pragma unroll
    for (int d=0;d<8;d++) ao[d]=0.0f;
    for (int f=0;f<64;f++){
      float qd=0;
      #pragma unroll
      for (int d=0;d<8;d++) qd += q[hh*8+d]*spm[hh][d][f];
      const float Qf = elu1_f(qd);
      den += Qf*sKVs[hh][f];
      #pragma unroll
      for (int d=0;d<8;d++) ao[d] += Qf*sKV[hh][f][d];
    }
    const float z = 1.0f/den;
    #pragma unroll
    for (int d=0;d<8;d++) att[hh*8+d] = ao[d]*z;
  }
  // proj + residual
  float hn[32];
  for (int o=0;o<32;o++){
    float p = sbp[o];
    #pragma unroll
    for (int i=0;i<32;i++) p += att[i]*swp[i][o];
    hn[o] = hx[o]+p;
  }
  // ln2
  mu=0;
  #pragma unroll
  for (int i=0;i<32;i++) mu += hn[i];
  mu *= (1.0f/32.0f);
  vs=0;
  #pragma unroll
  for (int i=0;i<32;i++){ float d=hn[i]-mu; vs += d*d; }
  inv = rsqrtf(vs*(1.0f/32.0f)+EPS);
  float m[32];
  #pragma unroll
  for (int i=0;i<32;i++) m[i] = (hn[i]-mu)*inv*s2g[i]+s2b[i];
  // FFN
  float f2[32];
  #pragma unroll
  for (int o=0;o<32;o++) f2[o]=sb2[o];
  for (int j=0;j<64;j++){
    float t1 = sb1[j];
    #pragma unroll
    for (int i=0;i<32;i++) t1 += m[i]*sw1[i][j];
    const float g = gelu_f(t1);
    #pragma unroll
    for (int o=0;o<32;o++) f2[o] += g*sw2[j][o];
  }
  #pragma unroll
  for (int i=0;i<32;i++) hn[i]+=f2[i];
  #pragma unroll
  for (int i=0;i<8;i++) hp[i] = make_float4(hn[4*i],hn[4*i+1],hn[4*i+2],hn[4*i+3]);
}

// ---------------------------------------------------------------------------
// Final: layernorm -> pool score s; softmax over N per batch; weighted sum; fc
// ---------------------------------------------------------------------------
__global__ __launch_bounds__(256) void k_pool_score(
    const float* __restrict__ hbuf, const float* __restrict__ ng,
    const float* __restrict__ nb, const float* __restrict__ pw,
    const float* __restrict__ pb, float* __restrict__ s)
{
  const int tok = blockIdx.x*256 + threadIdx.x;
  float hx[32];
  const float4* src = (const float4*)(hbuf + (size_t)tok*32);
  #pragma unroll
  for (int i=0;i<8;i++){ float4 v4=src[i]; hx[4*i]=v4.x; hx[4*i+1]=v4.y; hx[4*i+2]=v4.z; hx[4*i+3]=v4.w; }
  float mu=0;
  #pragma unroll
  for (int i=0;i<32;i++) mu += hx[i];
  mu *= (1.0f/32.0f);
  float vs=0;
  #pragma unroll
  for (int i=0;i<32;i++){ float d=hx[i]-mu; vs += d*d; }
  const float inv = rsqrtf(vs*(1.0f/32.0f)+EPS);
  float sv = pb[0];
  #pragma unroll
  for (int i=0;i<32;i++) sv += ((hx[i]-mu)*inv*ng[i]+nb[i])*pw[i];
  s[tok]=sv;
}

__global__ __launch_bounds__(256) void k_softmax_stats(
    const float* __restrict__ s, float* __restrict__ bmax, float* __restrict__ bsum)
{
  __shared__ float red[256];
  __shared__ float smax_sh;
  const int b = blockIdx.x, tid = threadIdx.x;
  const float* sbp = s + (size_t)b*TOKB;
  float mx = -INFINITY;
  for (int i=tid;i<TOKB;i+=256) mx = fmaxf(mx, sbp[i]);
  red[tid]=mx; __syncthreads();
  for (int st=128;st>0;st>>=1){ if(tid<st) red[tid]=fmaxf(red[tid],red[tid+st]); __syncthreads(); }
  if (tid==0) smax_sh = red[0];
  __syncthreads();
  const float smax = smax_sh;
  float acc=0.0f;
  for (int i=tid;i<TOKB;i+=256) acc += expf(sbp[i]-smax);
  __syncthreads();
  red[tid]=acc; __syncthreads();
  for (int st=128;st>0;st>>=1){ if(tid<st) red[tid]+=red[tid+st]; __syncthreads(); }
  if (tid==0){ bmax[b]=smax; bsum[b]=red[0]; }
}

__global__ __launch_bounds__(256) void k_pool_partial(
    const float* __restrict__ hbuf, const float* __restrict__ ng,
    const float* __restrict__ nb, const float* __restrict__ s,
    const float* __restrict__ bmax, float* __restrict__ pp)
{
  __shared__ float red[256][33];
  const int b = blockIdx.x/63, ch = blockIdx.x%63;
  const int tid = threadIdx.x;
  const int n = ch*256+tid;
  if (n < TOKB) {
    const int tok = b*TOKB+n;
    float hx[32];
    const float4* src = (const float4*)(hbuf + (size_t)tok*32);
    #pragma unroll
    for (int i=0;i<8;i++){ float4 v4=src[i]; hx[4*i]=v4.x; hx[4*i+1]=v4.y; hx[4*i+2]=v4.z; hx[4*i+3]=v4.w; }
    float mu=0;
    #pragma unroll
    for (int i=0;i<32;i++) mu += hx[i];
    mu *= (1.0f/32.0f);
    float vs=0;
    #pragma unroll
    for (int i=0;i<32;i++){ float d=hx[i]-mu; vs += d*d; }
    const float inv = rsqrtf(vs*(1.0f/32.0f)+EPS);
    const float w = expf(s[tok]-bmax[b]);
    #pragma unroll
    for (int i=0;i<32;i++) red[tid][i] = w*((hx[i]-mu)*inv*ng[i]+nb[i]);
  } else {
    #pragma unroll
    for (int i=0;i<32;i++) red[tid][i]=0.0f;
  }
  __syncthreads();
  if (tid<32){
    float acc=0.0f;
    for (int t=0;t<256;t++) acc += red[t][tid];
    pp[(size_t)blockIdx.x*32 + tid] = acc;
  }
}

__global__ __launch_bounds__(64) void k_pool_final(
    const float* __restrict__ pp, const float* __restrict__ bsum,
    const float* __restrict__ fcw, const float* __restrict__ fcb,
    float* __restrict__ out)
{
  __shared__ float sp[32];
  const int b = blockIdx.x, tid = threadIdx.x;
  if (tid<32){
    float acc=0.0f;
    for (int ch=0;ch<63;ch++) acc += pp[(size_t)(b*63+ch)*32+tid];
    sp[tid] = acc / bsum[b];
  }
  __syncthreads();
  if (tid<2){
    float v = fcb[tid];
    for (int o=0;o<32;o++) v += sp[o]*fcw[o*2+tid];
    out[b*2+tid]=v;
  }
}

extern "C" void kernel_launch(void* const* d_in, const int* in_sizes, int n_in,
                              void* d_out, int out_size, void* d_ws, size_t ws_size,
                              hipStream_t stream)
{
  const float* x      = (const float*)d_in[0];
  const float* band_w = (const float*)d_in[1];
  const float* pw_w   = (const float*)d_in[2];
  const float* bn_g   = (const float*)d_in[3];
  const float* bn_b   = (const float*)d_in[4];
  const float* bn_m   = (const float*)d_in[5];
  const float* bn_v   = (const float*)d_in[6];
  const float* ln1_g  = (const float*)d_in[7];
  const float* ln1_b  = (const float*)d_in[8];
  const float* wqkv   = (const float*)d_in[9];
  const float* proj   = (const float*)d_in[10];
  const float* wproj  = (const float*)d_in[11];
  const float* bprojp = (const float*)d_in[12];
  const float* ln2_g  = (const float*)d_in[13];
  const float* ln2_b  = (const float*)d_in[14];
  const float* w1     = (const float*)d_in[15];
  const float* b1     = (const float*)d_in[16];
  const float* w2     = (const float*)d_in[17];
  const float* b2     = (const float*)d_in[18];
  const float* norm_g = (const float*)d_in[19];
  const float* norm_b = (const float*)d_in[20];
  const float* pool_w = (const float*)d_in[21];
  const float* pool_b = (const float*)d_in[22];
  const float* fc_w   = (const float*)d_in[23];
  const float* fc_b   = (const float*)d_in[24];
  float* out = (float*)d_out;
  float* ws  = (float*)d_ws;

  float* hbuf  = ws;                       // 8,192,000 floats (32 MB)
  float* kvp   = hbuf + 8192000;           // 2000*2048 = 4,096,000
  float* p2    = kvp  + 4096000;           // 10*2048 = 20,480
  float* KV    = p2   + 20480;             // 2048
  float* KVs   = KV   + 2048;              // 256
  float* sbuf  = KVs  + 256;               // 256,000
  float* bmax  = sbuf + 256000;            // 16
  float* bsum  = bmax + 16;                // 16
  float* pp    = bsum + 16;                // 16*63*32 = 32,256

  k_tokenize<<<1024,256,0,stream>>>(x, band_w, pw_w, bn_g, bn_b, bn_m, bn_v, hbuf);
  for (int l=0;l<2;l++){
    k_kv_partial<<<2000,256,0,stream>>>(hbuf, ln1_g, ln1_b, wqkv, proj, kvp, l);
    k_kv_reduce1<<<80,256,0,stream>>>(kvp, p2);
    k_kv_reduce2<<<1,256,0,stream>>>(p2, KV, KVs);
    k_attn_ffn<<<1000,256,0,stream>>>(hbuf, ln1_g, ln1_b, wqkv, proj, wproj, bprojp,
                                      ln2_g, ln2_b, w1, b1, w2, b2, KV, KVs, l);
  }
  k_pool_score<<<1000,256,0,stream>>>(hbuf, norm_g, norm_b, pool_w, pool_b, sbuf);
  k_softmax_stats<<<16,256,0,stream>>>(sbuf, bmax, bsum);
  k_pool_partial<<<16*63,256,0,stream>>>(hbuf, norm_g, norm_b, sbuf, bmax, pp);
  k_pool_final<<<16,64,0,stream>>>(pp, bsum, fc_w, fc_b, out);
}

// Round 2
// 1129.405 us; speedup vs baseline: 1.0551x; 1.0551x over previous
//
#include <hip/hip_runtime.h>
#include <math.h>

#define NTOK   256000
#define TOKB   16000
#define EPS    1e-5f

__device__ __forceinline__ float gelu_f(float x){
  return 0.5f*x*(1.0f+erff(x*0.70710678118654752440f));
}
__device__ __forceinline__ float elu1_f(float x){
  return x>0.0f ? x+1.0f : __expf(x);   // elu(x)+1
}

// ---------------------------------------------------------------------------
// Tokenizer: band conv(51) -> 1x1 conv(4->32) -> BN -> GELU -> avgpool(4)
// ---------------------------------------------------------------------------
__global__ __launch_bounds__(256) void k_tokenize(
    const float* __restrict__ x, const float* __restrict__ band_w,
    const float* __restrict__ pw_w, const float* __restrict__ bn_g,
    const float* __restrict__ bn_b, const float* __restrict__ bn_m,
    const float* __restrict__ bn_v, float* __restrict__ hout)
{
  __shared__ float sx[1050];
  __shared__ float sbw[4][51];
  __shared__ float spw[32][4];
  __shared__ float sscale[32], sshift[32];
  const int tid = threadIdx.x;
  const int b = blockIdx.x >> 6, e = blockIdx.x & 63;
  const float* xr = x + (size_t)(b*64 + e)*1000;
  for (int i=tid;i<1050;i+=256){ int t=i-25; sx[i]=(t>=0&&t<1000)?xr[t]:0.0f; }
  for (int i=tid;i<204;i+=256){ sbw[i/51][i%51] = band_w[i]; }
  for (int i=tid;i<128;i+=256){ spw[i>>2][i&3] = pw_w[i]; }
  if (tid<32){ float sc = bn_g[tid]*rsqrtf(bn_v[tid]+EPS);
               sscale[tid]=sc; sshift[tid]=bn_b[tid]-bn_m[tid]*sc; }
  __syncthreads();
  const int tp = tid;
  if (tp < 250) {
    float acc[32];
    #pragma unroll
    for (int o=0;o<32;o++) acc[o]=0.0f;
    for (int j=0;j<4;j++){
      const int t = 4*tp+j;
      float c0=0,c1=0,c2=0,c3=0;
      for (int k=0;k<51;k++){
        float xv = sx[t+k];
        c0 += xv*sbw[0][k]; c1 += xv*sbw[1][k];
        c2 += xv*sbw[2][k]; c3 += xv*sbw[3][k];
      }
      #pragma unroll
      for (int o=0;o<32;o++){
        float hv = spw[o][0]*c0 + spw[o][1]*c1 + spw[o][2]*c2 + spw[o][3]*c3;
        hv = hv*sscale[o] + sshift[o];
        acc[o] += gelu_f(hv);
      }
    }
    const int tok = b*TOKB + e*250 + tp;
    float4* dst = (float4*)(hout + (size_t)tok*32);
    #pragma unroll
    for (int o8=0;o8<8;o8++)
      dst[o8] = make_float4(acc[o8*4]*0.25f, acc[o8*4+1]*0.25f,
                            acc[o8*4+2]*0.25f, acc[o8*4+3]*0.25f);
  }
}

// ---------------------------------------------------------------------------
// Pass A: per 128-token tile: ln1 -> k,v -> K-features -> partial KV[h,f,d]
// ---------------------------------------------------------------------------
__global__ __launch_bounds__(256) void k_kv_partial(
    const float* __restrict__ hbuf, const float* __restrict__ ln1_g,
    const float* __restrict__ ln1_b, const float* __restrict__ wqkv,
    const float* __restrict__ proj_mat, float* __restrict__ kvpart, int l)
{
  __shared__ float sk[128][33];
  __shared__ float sv[128][33];
  __shared__ float swk[32][64];   // wqkv cols 32..95 (k then v)
  __shared__ float sg[32], sb[32];
  const int tid = threadIdx.x;
  const float* W = wqkv + l*32*96;
  for (int i=tid;i<2048;i+=256){ swk[i>>6][i&63] = W[(i>>6)*96 + 32 + (i&63)]; }
  if (tid<32){ sg[tid]=ln1_g[l*32+tid]; sb[tid]=ln1_b[l*32+tid]; }
  __syncthreads();
  {
    const int tloc = tid>>1, half = tid&1;
    const int tok = blockIdx.x*128 + tloc;
    float hx[32];
    const float4* src = (const float4*)(hbuf + (size_t)tok*32);
    #pragma unroll
    for (int i=0;i<8;i++){ float4 v4=src[i]; hx[4*i]=v4.x; hx[4*i+1]=v4.y; hx[4*i+2]=v4.z; hx[4*i+3]=v4.w; }
    float mu=0;
    #pragma unroll
    for (int i=0;i<32;i++) mu += hx[i];
    mu *= (1.0f/32.0f);
    float vs=0;
    #pragma unroll
    for (int i=0;i<32;i++){ float d=hx[i]-mu; vs += d*d; }
    const float inv = rsqrtf(vs*(1.0f/32.0f)+EPS);
    float xn[32];
    #pragma unroll
    for (int i=0;i<32;i++) xn[i] = (hx[i]-mu)*inv*sg[i]+sb[i];
    const int j0 = half*16;
    #pragma unroll 4
    for (int jj=0;jj<16;jj++){
      const int j = j0+jj;
      float ka=0, va=0;
      #pragma unroll
      for (int i=0;i<32;i++){ ka += xn[i]*swk[i][j]; va += xn[i]*swk[i][32+j]; }
      sk[tloc][j]=ka; sv[tloc][j]=va;
    }
  }
  __syncthreads();
  const int hh = tid>>6, f = tid&63;
  float pmv[8];
  #pragma unroll
  for (int d=0;d<8;d++) pmv[d] = proj_mat[((size_t)(l*4+hh)*8+d)*64 + f];
  float acc[8];
  #pragma unroll
  for (int d=0;d<8;d++) acc[d]=0.0f;
  #pragma unroll 4
  for (int t=0;t<128;t++){
    float kd=0;
    #pragma unroll
    for (int d=0;d<8;d++) kd += sk[t][hh*8+d]*pmv[d];
    const float Kf = elu1_f(kd);
    #pragma unroll
    for (int d=0;d<8;d++) acc[d] += Kf*sv[t][hh*8+d];
  }
  float* dst = kvpart + (size_t)blockIdx.x*2048 + tid*8;
  #pragma unroll
  for (int d=0;d<8;d++) dst[d]=acc[d];
}

// fixed-order hierarchical KV reduction: 2000 partials -> 10 chunks -> final
__global__ __launch_bounds__(256) void k_kv_reduce1(
    const float* __restrict__ kvpart, float* __restrict__ p2)
{
  const int chunk = blockIdx.x >> 3;                 // 0..9
  const int e = (blockIdx.x&7)*256 + threadIdx.x;    // 0..2047
  float acc=0.0f;
  const int base = chunk*200;
  for (int ab=0; ab<200; ab++) acc += kvpart[(size_t)(base+ab)*2048 + e];
  p2[chunk*2048 + e] = acc;
}

__global__ __launch_bounds__(256) void k_kv_reduce2(
    const float* __restrict__ p2, float* __restrict__ KV, float* __restrict__ KVs)
{
  const int hf = threadIdx.x;
  float acc[8];
  #pragma unroll
  for (int d=0;d<8;d++) acc[d]=0.0f;
  for (int c=0;c<10;c++){
    #pragma unroll
    for (int d=0;d<8;d++) acc[d] += p2[c*2048 + hf*8 + d];
  }
  float s=0.0f;
  #pragma unroll
  for (int d=0;d<8;d++){ KV[hf*8+d]=acc[d]; s+=acc[d]; }
  KVs[hf]=s;
}

// ---------------------------------------------------------------------------
// Pass C: per token, fully register-resident (no runtime-indexed arrays):
// ln1 -> per-head {q_h, Qfeat, attn, proj-accum} -> +res -> ln2 -> FFN -> +res
// ---------------------------------------------------------------------------
__global__ __launch_bounds__(256) void k_attn_ffn(
    float* __restrict__ hbuf,
    const float* __restrict__ ln1_g, const float* __restrict__ ln1_b,
    const float* __restrict__ wqkv, const float* __restrict__ proj_mat,
    const float* __restrict__ wproj, const float* __restrict__ bproj,
    const float* __restrict__ ln2_g, const float* __restrict__ ln2_b,
    const float* __restrict__ w1, const float* __restrict__ b1,
    const float* __restrict__ w2, const float* __restrict__ b2,
    const float* __restrict__ KV, const float* __restrict__ KVs, int l)
{
  __shared__ float swq[32][32];
  __shared__ float spm[4][8][64];
  __shared__ float sKV[4][64][8];
  __shared__ float sKVs[4][64];
  __shared__ float swp[32][32];
  __shared__ float sw1[32][64];
  __shared__ float sw2[64][32];
  __shared__ float s1g[32],s1b[32],s2g[32],s2b[32],sbp[32],sb1[64],sb2[32];
  const int tid = threadIdx.x;
  for (int i=tid;i<1024;i+=256) swq[i>>5][i&31] = wqkv[l*3072 + (i>>5)*96 + (i&31)];
  for (int i=tid;i<2048;i+=256) (&spm[0][0][0])[i] = proj_mat[l*2048+i];
  for (int i=tid;i<2048;i+=256) (&sKV[0][0][0])[i] = KV[i];
  (&sKVs[0][0])[tid] = KVs[tid];
  for (int i=tid;i<1024;i+=256) (&swp[0][0])[i] = wproj[l*1024+i];
  for (int i=tid;i<2048;i+=256) (&sw1[0][0])[i] = w1[l*2048+i];
  for (int i=tid;i<2048;i+=256) (&sw2[0][0])[i] = w2[l*2048+i];
  if (tid<32){ s1g[tid]=ln1_g[l*32+tid]; s1b[tid]=ln1_b[l*32+tid];
               s2g[tid]=ln2_g[l*32+tid]; s2b[tid]=ln2_b[l*32+tid];
               sbp[tid]=bproj[l*32+tid]; sb2[tid]=b2[l*32+tid]; }
  if (tid<64) sb1[tid]=b1[l*64+tid];
  __syncthreads();

  const int tok = blockIdx.x*256 + tid;
  float hx[32];
  float4* hp = (float4*)(hbuf + (size_t)tok*32);
  #pragma unroll
  for (int i=0;i<8;i++){ float4 v4=hp[i]; hx[4*i]=v4.x; hx[4*i+1]=v4.y; hx[4*i+2]=v4.z; hx[4*i+3]=v4.w; }
  // ln1
  float mu=0;
  #pragma unroll
  for (int i=0;i<32;i++) mu += hx[i];
  mu *= (1.0f/32.0f);
  float vs=0;
  #pragma unroll
  for (int i=0;i<32;i++){ float d=hx[i]-mu; vs += d*d; }
  float inv = rsqrtf(vs*(1.0f/32.0f)+EPS);
  float xn[32];
  #pragma unroll
  for (int i=0;i<32;i++) xn[i] = (hx[i]-mu)*inv*s1g[i]+s1b[i];

  // attention, streamed per head; accumulate projection directly
  float p[32];
  #pragma unroll
  for (int o=0;o<32;o++) p[o]=sbp[o];
  #pragma unroll
  for (int hh=0;hh<4;hh++){
    float qh[8];
    #pragma unroll
    for (int d=0;d<8;d++){
      float a=0;
      #pragma unroll
      for (int i=0;i<32;i++) a += xn[i]*swq[i][hh*8+d];
      qh[d]=a;
    }
    float den=0;
    float ao[8];
    #pragma unroll
    for (int d=0;d<8;d++) ao[d]=0.0f;
    #pragma unroll 4
    for (int f=0;f<64;f++){
      float qd=0;
      #pragma unroll
      for (int d=0;d<8;d++) qd += qh[d]*spm[hh][d][f];
      const float Qf = elu1_f(qd);
      den += Qf*sKVs[hh][f];
      #pragma unroll
      for (int d=0;d<8;d++) ao[d] += Qf*sKV[hh][f][d];
    }
    const float z = 1.0f/den;
    #pragma unroll
    for (int d=0;d<8;d++) ao[d] *= z;
    #pragma unroll
    for (int o=0;o<32;o++){
      float a=0;
      #pragma unroll
      for (int d=0;d<8;d++) a += ao[d]*swp[hh*8+d][o];
      p[o] += a;
    }
  }
  // residual
  float hn[32];
  #pragma unroll
  for (int o=0;o<32;o++) hn[o] = hx[o]+p[o];
  // ln2 (reuse xn as m)
  mu=0;
  #pragma unroll
  for (int i=0;i<32;i++) mu += hn[i];
  mu *= (1.0f/32.0f);
  vs=0;
  #pragma unroll
  for (int i=0;i<32;i++){ float d=hn[i]-mu; vs += d*d; }
  inv = rsqrtf(vs*(1.0f/32.0f)+EPS);
  #pragma unroll
  for (int i=0;i<32;i++) xn[i] = (hn[i]-mu)*inv*s2g[i]+s2b[i];
  // FFN
  float f2[32];
  #pragma unroll
  for (int o=0;o<32;o++) f2[o]=sb2[o];
  #pragma unroll 2
  for (int j=0;j<64;j++){
    float t1 = sb1[j];
    #pragma unroll
    for (int i=0;i<32;i++) t1 += xn[i]*sw1[i][j];
    const float g = gelu_f(t1);
    #pragma unroll
    for (int o=0;o<32;o++) f2[o] += g*sw2[j][o];
  }
  #pragma unroll
  for (int i=0;i<32;i++) hn[i]+=f2[i];
  #pragma unroll
  for (int i=0;i<8;i++) hp[i] = make_float4(hn[4*i],hn[4*i+1],hn[4*i+2],hn[4*i+3]);
}

// ---------------------------------------------------------------------------
// Final: layernorm -> pool score s; softmax over N per batch; weighted sum; fc
// ---------------------------------------------------------------------------
__global__ __launch_bounds__(256) void k_pool_score(
    const float* __restrict__ hbuf, const float* __restrict__ ng,
    const float* __restrict__ nb, const float* __restrict__ pw,
    const float* __restrict__ pb, float* __restrict__ s)
{
  const int tok = blockIdx.x*256 + threadIdx.x;
  float hx[32];
  const float4* src = (const float4*)(hbuf + (size_t)tok*32);
  #pragma unroll
  for (int i=0;i<8;i++){ float4 v4=src[i]; hx[4*i]=v4.x; hx[4*i+1]=v4.y; hx[4*i+2]=v4.z; hx[4*i+3]=v4.w; }
  float mu=0;
  #pragma unroll
  for (int i=0;i<32;i++) mu += hx[i];
  mu *= (1.0f/32.0f);
  float vs=0;
  #pragma unroll
  for (int i=0;i<32;i++){ float d=hx[i]-mu; vs += d*d; }
  const float inv = rsqrtf(vs*(1.0f/32.0f)+EPS);
  float sv = pb[0];
  #pragma unroll
  for (int i=0;i<32;i++) sv += ((hx[i]-mu)*inv*ng[i]+nb[i])*pw[i];
  s[tok]=sv;
}

__global__ __launch_bounds__(256) void k_softmax_stats(
    const float* __restrict__ s, float* __restrict__ bmax, float* __restrict__ bsum)
{
  __shared__ float red[256];
  __shared__ float smax_sh;
  const int b = blockIdx.x, tid = threadIdx.x;
  const float* sbp = s + (size_t)b*TOKB;
  float mx = -INFINITY;
  for (int i=tid;i<TOKB;i+=256) mx = fmaxf(mx, sbp[i]);
  red[tid]=mx; __syncthreads();
  for (int st=128;st>0;st>>=1){ if(tid<st) red[tid]=fmaxf(red[tid],red[tid+st]); __syncthreads(); }
  if (tid==0) smax_sh = red[0];
  __syncthreads();
  const float smax = smax_sh;
  float acc=0.0f;
  for (int i=tid;i<TOKB;i+=256) acc += __expf(sbp[i]-smax);
  __syncthreads();
  red[tid]=acc; __syncthreads();
  for (int st=128;st>0;st>>=1){ if(tid<st) red[tid]+=red[tid+st]; __syncthreads(); }
  if (tid==0){ bmax[b]=smax; bsum[b]=red[0]; }
}

__global__ __launch_bounds__(256) void k_pool_partial(
    const float* __restrict__ hbuf, const float* __restrict__ ng,
    const float* __restrict__ nb, const float* __restrict__ s,
    const float* __restrict__ bmax, float* __restrict__ pp)
{
  __shared__ float red[256][33];
  const int b = blockIdx.x/63, ch = blockIdx.x%63;
  const int tid = threadIdx.x;
  const int n = ch*256+tid;
  if (n < TOKB) {
    const int tok = b*TOKB+n;
    float hx[32];
    const float4* src = (const float4*)(hbuf + (size_t)tok*32);
    #pragma unroll
    for (int i=0;i<8;i++){ float4 v4=src[i]; hx[4*i]=v4.x; hx[4*i+1]=v4.y; hx[4*i+2]=v4.z; hx[4*i+3]=v4.w; }
    float mu=0;
    #pragma unroll
    for (int i=0;i<32;i++) mu += hx[i];
    mu *= (1.0f/32.0f);
    float vs=0;
    #pragma unroll
    for (int i=0;i<32;i++){ float d=hx[i]-mu; vs += d*d; }
    const float inv = rsqrtf(vs*(1.0f/32.0f)+EPS);
    const float w = __expf(s[tok]-bmax[b]);
    #pragma unroll
    for (int i=0;i<32;i++) red[tid][i] = w*((hx[i]-mu)*inv*ng[i]+nb[i]);
  } else {
    #pragma unroll
    for (int i=0;i<32;i++) red[tid][i]=0.0f;
  }
  __syncthreads();
  if (tid<32){
    float acc=0.0f;
    for (int t=0;t<256;t++) acc += red[t][tid];
    pp[(size_t)blockIdx.x*32 + tid] = acc;
  }
}

__global__ __launch_bounds__(64) void k_pool_final(
    const float* __restrict__ pp, const float* __restrict__ bsum,
    const float* __restrict__ fcw, const float* __restrict__ fcb,
    float* __restrict__ out)
{
  __shared__ float sp[32];
  const int b = blockIdx.x, tid = threadIdx.x;
  if (tid<32){
    float acc=0.0f;
    for (int ch=0;ch<63;ch++) acc += pp[(size_t)(b*63+ch)*32+tid];
    sp[tid] = acc / bsum[b];
  }
  __syncthreads();
  if (tid<2){
    float v = fcb[tid];
    for (int o=0;o<32;o++) v += sp[o]*fcw[o*2+tid];
    out[b*2+tid]=v;
  }
}

extern "C" void kernel_launch(void* const* d_in, const int* in_sizes, int n_in,
                              void* d_out, int out_size, void* d_ws, size_t ws_size,
                              hipStream_t stream)
{
  const float* x      = (const float*)d_in[0];
  const float* band_w = (const float*)d_in[1];
  const float* pw_w   = (const float*)d_in[2];
  const float* bn_g   = (const float*)d_in[3];
  const float* bn_b   = (const float*)d_in[4];
  const float* bn_m   = (const float*)d_in[5];
  const float* bn_v   = (const float*)d_in[6];
  const float* ln1_g  = (const float*)d_in[7];
  const float* ln1_b  = (const float*)d_in[8];
  const float* wqkv   = (const float*)d_in[9];
  const float* proj   = (const float*)d_in[10];
  const float* wproj  = (const float*)d_in[11];
  const float* bprojp = (const float*)d_in[12];
  const float* ln2_g  = (const float*)d_in[13];
  const float* ln2_b  = (const float*)d_in[14];
  const float* w1     = (const float*)d_in[15];
  const float* b1     = (const float*)d_in[16];
  const float* w2     = (const float*)d_in[17];
  const float* b2     = (const float*)d_in[18];
  const float* norm_g = (const float*)d_in[19];
  const float* norm_b = (const float*)d_in[20];
  const float* pool_w = (const float*)d_in[21];
  const float* pool_b = (const float*)d_in[22];
  const float* fc_w   = (const float*)d_in[23];
  const float* fc_b   = (const float*)d_in[24];
  float* out = (float*)d_out;
  float* ws  = (float*)d_ws;

  float* hbuf  = ws;                       // 8,192,000 floats (32 MB)
  float* kvp   = hbuf + 8192000;           // 2000*2048 = 4,096,000
  float* p2    = kvp  + 4096000;           // 10*2048 = 20,480
  float* KV    = p2   + 20480;             // 2048
  float* KVs   = KV   + 2048;              // 256
  float* sbuf  = KVs  + 256;               // 256,000
  float* bmax  = sbuf + 256000;            // 16
  float* bsum  = bmax + 16;                // 16
  float* pp    = bsum + 16;                // 16*63*32 = 32,256

  k_tokenize<<<1024,256,0,stream>>>(x, band_w, pw_w, bn_g, bn_b, bn_m, bn_v, hbuf);
  for (int l=0;l<2;l++){
    k_kv_partial<<<2000,256,0,stream>>>(hbuf, ln1_g, ln1_b, wqkv, proj, kvp, l);
    k_kv_reduce1<<<80,256,0,stream>>>(kvp, p2);
    k_kv_reduce2<<<1,256,0,stream>>>(p2, KV, KVs);
    k_attn_ffn<<<1000,256,0,stream>>>(hbuf, ln1_g, ln1_b, wqkv, proj, wproj, bprojp,
                                      ln2_g, ln2_b, w1, b1, w2, b2, KV, KVs, l);
  }
  k_pool_score<<<1000,256,0,stream>>>(hbuf, norm_g, norm_b, pool_w, pool_b, sbuf);
  k_softmax_stats<<<16,256,0,stream>>>(sbuf, bmax, bsum);
  k_pool_partial<<<16*63,256,0,stream>>>(hbuf, norm_g, norm_b, sbuf, bmax, pp);
  k_pool_final<<<16,64,0,stream>>>(pp, bsum, fc_w, fc_b, out);
}